// Round 5
// baseline (650.257 us; speedup 1.0000x reference)
//
#include <hip/hip_runtime.h>
#include <stdint.h>
#include <stddef.h>

typedef short bf16x8 __attribute__((ext_vector_type(8)));
typedef float f32x4 __attribute__((ext_vector_type(4)));

// ---------------- helpers ----------------
static __device__ __forceinline__ unsigned enc_min(float v) {
  unsigned u = __float_as_uint(v);
  return (u & 0x80000000u) ? ~u : (u | 0x80000000u);
}
static __device__ __forceinline__ unsigned short f2bf(float f) {
  unsigned u = __float_as_uint(f);
  u += 0x7fffu + ((u >> 16) & 1u);
  return (unsigned short)(u >> 16);
}
static __device__ __forceinline__ float bf2f(unsigned short b) {
  return __uint_as_float(((unsigned)b) << 16);
}

// ---------------- degree count, XCD-binned ----------------
__global__ void k_count(const int* __restrict__ edge, int E, int N, int* __restrict__ cnt) {
  int grp = blockIdx.x & 7;
  int bslot = blockIdx.x >> 3;
  int nslot = gridDim.x >> 3;
  int lo = (int)(((long long)N * grp) >> 3);
  int hi = (int)(((long long)N * (grp + 1)) >> 3);
  for (int e = bslot * blockDim.x + threadIdx.x; e < E; e += nslot * blockDim.x) {
    int d = edge[E + e];
    if (d >= lo && d < hi) atomicAdd(&cnt[d], 1);
  }
}

// ---------------- block inclusive scan (1024/block) ----------------
__global__ void k_scan1(const int* __restrict__ cnt, int N,
                        int* __restrict__ incl, int* __restrict__ bsum) {
  __shared__ int sm[1024];
  int tid = threadIdx.x;
  int i = blockIdx.x * 1024 + tid;
  int v = (i < N) ? cnt[i] : 0;
  sm[tid] = v;
  __syncthreads();
  for (int off = 1; off < 1024; off <<= 1) {
    int t = (tid >= off) ? sm[tid - off] : 0;
    __syncthreads();
    sm[tid] += t;
    __syncthreads();
  }
  if (i < N) incl[i] = sm[tid];
  if (tid == 1023) bsum[blockIdx.x] = sm[1023];
}

// ---------------- scan of block sums (nb <= 128) ----------------
__global__ void k_scan2(const int* __restrict__ bsum, int nb, int* __restrict__ boff) {
  __shared__ int sm[128];
  int tid = threadIdx.x;
  int v = (tid < nb) ? bsum[tid] : 0;
  sm[tid] = v;
  __syncthreads();
  for (int off = 1; off < 128; off <<= 1) {
    int t = (tid >= off) ? sm[tid - off] : 0;
    __syncthreads();
    sm[tid] += t;
    __syncthreads();
  }
  if (tid < nb) boff[tid] = sm[tid] - v;  // exclusive
}

// ---------------- row_ptr / cursor / dinv ----------------
__global__ void k_aux(const int* __restrict__ cnt, const int* __restrict__ incl,
                      const int* __restrict__ boff, int N, int E,
                      int* __restrict__ row_ptr, int* __restrict__ cursor,
                      float* __restrict__ dinv) {
  int i = blockIdx.x * blockDim.x + threadIdx.x;
  if (i < N) {
    int rp = incl[i] - cnt[i] + boff[i >> 10];
    row_ptr[i] = rp;
    cursor[i] = rp;
    dinv[i] = 1.0f / sqrtf((float)(cnt[i] + 1));  // +1 self-loop
  } else if (i == N) {
    row_ptr[N] = E;
  }
}

// ---------------- CSR fill (bucket by dst, store src), XCD-binned ----------------
__global__ void k_fill(const int* __restrict__ edge, int E, int N,
                       int* __restrict__ cursor, int* __restrict__ srcs) {
  int grp = blockIdx.x & 7;
  int bslot = blockIdx.x >> 3;
  int nslot = gridDim.x >> 3;
  int lo = (int)(((long long)N * grp) >> 3);
  int hi = (int)(((long long)N * (grp + 1)) >> 3);
  for (int e = bslot * blockDim.x + threadIdx.x; e < E; e += nslot * blockDim.x) {
    int d = edge[E + e];
    if (d >= lo && d < hi) {
      int s = edge[e];
      int pos = atomicAdd(&cursor[d], 1);
      srcs[pos] = s;
    }
  }
}

// ---------------- weight prep: W[k][n] fp32 -> Wt_hi/Wt_lo[n][k] bf16 ----------------
// bf16x3 split: w = hi + lo + O(2^-18 w). 40960 total elements across W1,W2,W3.
__global__ void k_prepw(const float* __restrict__ W1, const float* __restrict__ W2,
                        const float* __restrict__ W3,
                        unsigned short* __restrict__ w1h, unsigned short* __restrict__ w1l,
                        unsigned short* __restrict__ w2h, unsigned short* __restrict__ w2l,
                        unsigned short* __restrict__ w3h, unsigned short* __restrict__ w3l) {
  const int K = 128;
  int idx = blockIdx.x * 256 + threadIdx.x;
  const float* W;
  unsigned short *oh, *ol;
  int Nn, base;
  if (idx < 16384) { W = W1; Nn = 128; oh = w1h; ol = w1l; base = idx; }
  else if (idx < 32768) { W = W2; Nn = 128; oh = w2h; ol = w2l; base = idx - 16384; }
  else if (idx < 40960) { W = W3; Nn = 64; oh = w3h; ol = w3l; base = idx - 32768; }
  else return;
  int n = base / K, k = base % K;
  float w = W[(size_t)k * Nn + n];
  unsigned short h = f2bf(w);
  unsigned short l = f2bf(w - bf2f(h));
  oh[(size_t)n * K + k] = h;
  ol[(size_t)n * K + k] = l;
}

// ---------------- MFMA GEMM: P = bf16((A @ W) * dinv[row]), sliced layout ----------------
// bf16x3: D = Ah*Bh + Ah*Bl + Al*Bh (fp32 MFMA accum) -> ~fp32 accuracy.
// Block: 256 thr = 4 waves; block tile 64 rows x (NF*16) cols; wave w owns rows
// [w*16, w*16+16). mfma_f32_16x16x32_bf16 layouts (m89-verified):
//   A: m = lane&15, k = quad*8 + j;  B: n = lane&15, k = quad*8 + j
//   D: col = lane&15, row = quad*4 + reg
// P layout: slice s (16 ch) contiguous: P[s*M*16 + row*16 + ch%16]; col frag nf == slice.
template <int NF>
__global__ __launch_bounds__(256) void k_gemm_mfma(const float* __restrict__ A,
                                                   const unsigned short* __restrict__ Wth,
                                                   const unsigned short* __restrict__ Wtl,
                                                   const float* __restrict__ dinv,
                                                   unsigned short* __restrict__ P, int M) {
  const int K = 128;
  __shared__ unsigned short Ah[64][136];  // row stride 272 B (16-aligned for ds_read_b128)
  __shared__ unsigned short Al[64][136];
  int tid = threadIdx.x;
  int m0 = blockIdx.x * 64;

  // stage A tile (64 x 128 fp32) as bf16 hi/lo
#pragma unroll
  for (int q = 0; q < 8; ++q) {
    int f = q * 256 + tid;  // 0..2047 -> 64 rows x 32 float4
    int m = f >> 5, k4 = f & 31;
    int row = m0 + m;
    if (row >= M) row = M - 1;  // clamp; garbage rows never stored
    float4 v = *(const float4*)&A[(size_t)row * K + k4 * 4];
    float e0 = v.x, e1 = v.y, e2 = v.z, e3 = v.w;
    unsigned short h0 = f2bf(e0), h1 = f2bf(e1), h2 = f2bf(e2), h3 = f2bf(e3);
    unsigned short l0 = f2bf(e0 - bf2f(h0)), l1 = f2bf(e1 - bf2f(h1));
    unsigned short l2 = f2bf(e2 - bf2f(h2)), l3 = f2bf(e3 - bf2f(h3));
    uint2 hh, ll;
    hh.x = (unsigned)h0 | ((unsigned)h1 << 16);
    hh.y = (unsigned)h2 | ((unsigned)h3 << 16);
    ll.x = (unsigned)l0 | ((unsigned)l1 << 16);
    ll.y = (unsigned)l2 | ((unsigned)l3 << 16);
    *(uint2*)&Ah[m][k4 * 4] = hh;
    *(uint2*)&Al[m][k4 * 4] = ll;
  }
  __syncthreads();

  int w = tid >> 6, lane = tid & 63;
  int mloc = lane & 15, quad = lane >> 4;
  f32x4 acc[NF];
#pragma unroll
  for (int nf = 0; nf < NF; ++nf) acc[nf] = (f32x4){0.f, 0.f, 0.f, 0.f};

  const unsigned short* arow_h = &Ah[w * 16 + mloc][quad * 8];
  const unsigned short* arow_l = &Al[w * 16 + mloc][quad * 8];
#pragma unroll
  for (int kc = 0; kc < K; kc += 32) {
    bf16x8 ah = *(const bf16x8*)(arow_h + kc);
    bf16x8 al = *(const bf16x8*)(arow_l + kc);
#pragma unroll
    for (int nf = 0; nf < NF; ++nf) {
      size_t boff = (size_t)(nf * 16 + mloc) * K + kc + quad * 8;
      bf16x8 bh = *(const bf16x8*)&Wth[boff];
      bf16x8 bl = *(const bf16x8*)&Wtl[boff];
      acc[nf] = __builtin_amdgcn_mfma_f32_16x16x32_bf16(al, bh, acc[nf], 0, 0, 0);
      acc[nf] = __builtin_amdgcn_mfma_f32_16x16x32_bf16(ah, bl, acc[nf], 0, 0, 0);
      acc[nf] = __builtin_amdgcn_mfma_f32_16x16x32_bf16(ah, bh, acc[nf], 0, 0, 0);
    }
  }

  // epilogue: row = m0 + w*16 + quad*4 + reg, col = nf*16 + mloc
  int rbase = m0 + w * 16 + quad * 4;
  float dv[4];
#pragma unroll
  for (int r = 0; r < 4; ++r) dv[r] = (rbase + r < M) ? dinv[rbase + r] : 0.f;
#pragma unroll
  for (int nf = 0; nf < NF; ++nf) {
#pragma unroll
    for (int r = 0; r < 4; ++r) {
      int row = rbase + r;
      if (row < M) P[(size_t)nf * M * 16 + (size_t)row * 16 + mloc] = f2bf(acc[nf][r] * dv[r]);
    }
  }
}

// ---------------- sliced aggregation ----------------
// grid = ceil(N/32) * NS; blockIdx % NS = slice -> one XCD's L2 holds the
// 3.2 MB slice. Block: 256 thr = 4 waves; wave = 8 nodes x 8 ushort2 lanes.
template <int C, int RELU>
__global__ __launch_bounds__(256) void k_agg2(const unsigned short* __restrict__ P,
                                              const int* __restrict__ row_ptr,
                                              const int* __restrict__ srcs,
                                              const float* __restrict__ dinv,
                                              const float* __restrict__ bias,
                                              float* __restrict__ Hout, int N) {
  const int NS = C / 16;
  const int CAP = 768;
  __shared__ int s_idx[CAP];
  __shared__ int s_rp[33];
  int tid = threadIdx.x;
  int grp = blockIdx.x / NS;
  int s = blockIdx.x % NS;
  const unsigned short* Ps = P + (size_t)s * N * 16;

  int base = grp * 32;
  if (tid < 33) {
    int node = base + tid;
    s_rp[tid] = row_ptr[node < N ? node : N];
  }
  __syncthreads();
  int e0 = s_rp[0], e1 = s_rp[32];

  int wv = tid >> 6, lane = tid & 63;
  int nb = wv * 8 + (lane >> 3);
  int cp = lane & 7;
  int d = base + nb;
  bool valid = d < N;
  int lo_n = s_rp[nb], hi_n = s_rp[nb + 1];

  float a0 = 0.f, a1 = 0.f;
  if (valid) {
    unsigned v = *(const unsigned*)&Ps[(size_t)d * 16 + cp * 2];
    a0 = __uint_as_float(v << 16);
    a1 = __uint_as_float(v & 0xffff0000u);
  }

  for (int w0 = e0; w0 < e1; w0 += CAP) {
    int wend = min(w0 + CAP, e1);
    int cnt = wend - w0;
    __syncthreads();
    for (int t = tid; t < cnt; t += 256) s_idx[t] = srcs[w0 + t];
    __syncthreads();
    int lo = max(lo_n, w0), hi = min(hi_n, wend);
    int j = lo;
    for (; j + 4 <= hi; j += 4) {
      int i0 = s_idx[j - w0 + 0], i1 = s_idx[j - w0 + 1];
      int i2 = s_idx[j - w0 + 2], i3 = s_idx[j - w0 + 3];
      unsigned v0 = *(const unsigned*)&Ps[(size_t)i0 * 16 + cp * 2];
      unsigned v1 = *(const unsigned*)&Ps[(size_t)i1 * 16 + cp * 2];
      unsigned v2 = *(const unsigned*)&Ps[(size_t)i2 * 16 + cp * 2];
      unsigned v3 = *(const unsigned*)&Ps[(size_t)i3 * 16 + cp * 2];
      a0 += __uint_as_float(v0 << 16); a1 += __uint_as_float(v0 & 0xffff0000u);
      a0 += __uint_as_float(v1 << 16); a1 += __uint_as_float(v1 & 0xffff0000u);
      a0 += __uint_as_float(v2 << 16); a1 += __uint_as_float(v2 & 0xffff0000u);
      a0 += __uint_as_float(v3 << 16); a1 += __uint_as_float(v3 & 0xffff0000u);
    }
    for (; j < hi; ++j) {
      int i0 = s_idx[j - w0];
      unsigned v0 = *(const unsigned*)&Ps[(size_t)i0 * 16 + cp * 2];
      a0 += __uint_as_float(v0 << 16);
      a1 += __uint_as_float(v0 & 0xffff0000u);
    }
  }

  if (valid) {
    int c = s * 16 + cp * 2;
    float dvv = dinv[d];
    float h0 = dvv * a0 + bias[c];
    float h1 = dvv * a1 + bias[c + 1];
    if (RELU) { h0 = fmaxf(h0, 0.f); h1 = fmaxf(h1, 0.f); }
    *(float2*)&Hout[(size_t)d * C + c] = make_float2(h0, h1);
  }
}

// ---------------- min pool over nodes ----------------
__global__ void k_minpool(const float* __restrict__ H, int N, unsigned* __restrict__ minenc) {
  __shared__ float sm[256];
  int tid = threadIdx.x;
  int c = tid & 63;
  int r = (blockIdx.x * blockDim.x + tid) >> 6;
  int stride = (gridDim.x * blockDim.x) >> 6;
  float mn = 3.402823466e38f;
  for (; r < N; r += stride) mn = fminf(mn, H[(size_t)r * 64 + c]);
  sm[tid] = mn;
  __syncthreads();
  if (tid < 64) {
    mn = fminf(fminf(sm[tid], sm[tid + 64]), fminf(sm[tid + 128], sm[tid + 192]));
    atomicMin(&minenc[c], enc_min(mn));
  }
}

__global__ void k_decode(const unsigned* __restrict__ minenc, float* __restrict__ out) {
  int c = threadIdx.x;
  unsigned k = minenc[c];
  unsigned u = (k & 0x80000000u) ? (k & 0x7FFFFFFFu) : ~k;
  out[c] = __uint_as_float(u);
}

// ---------------- launch ----------------
extern "C" void kernel_launch(void* const* d_in, const int* in_sizes, int n_in,
                              void* d_out, int out_size, void* d_ws, size_t ws_size,
                              hipStream_t stream) {
  const float* X  = (const float*)d_in[0];
  const int* edge = (const int*)d_in[1];
  const float* W1 = (const float*)d_in[2];
  const float* b1 = (const float*)d_in[3];
  const float* W2 = (const float*)d_in[4];
  const float* b2 = (const float*)d_in[5];
  const float* W3 = (const float*)d_in[6];
  const float* b3 = (const float*)d_in[7];
  float* out = (float*)d_out;

  const int IN_CH = 128;
  int N = in_sizes[0] / IN_CH;
  int E = in_sizes[1] / 2;

  char* ws = (char*)d_ws;
  size_t off = 0;
  auto alloc = [&](size_t bytes) {
    void* p = ws + off;
    off = (off + bytes + 255) & ~(size_t)255;
    return p;
  };
  unsigned short* P = (unsigned short*)alloc((size_t)N * 128 * 2);  // 25.6 MB bf16, sliced
  float* H       = (float*)alloc((size_t)N * 128 * 4);              // 51.2 MB
  int* srcs      = (int*)alloc((size_t)E * 4);                      // 6.4 MB
  int* cnt       = (int*)alloc((size_t)N * 4);
  int* incl      = (int*)alloc((size_t)N * 4);
  int* row_ptr   = (int*)alloc((size_t)(N + 1) * 4);
  int* cursor    = (int*)alloc((size_t)N * 4);
  float* dinv    = (float*)alloc((size_t)N * 4);
  int* bsum      = (int*)alloc(1024);
  int* boff      = (int*)alloc(1024);
  unsigned* minenc = (unsigned*)alloc(256);
  unsigned short* w1h = (unsigned short*)alloc(16384 * 2);
  unsigned short* w1l = (unsigned short*)alloc(16384 * 2);
  unsigned short* w2h = (unsigned short*)alloc(16384 * 2);
  unsigned short* w2l = (unsigned short*)alloc(16384 * 2);
  unsigned short* w3h = (unsigned short*)alloc(8192 * 2);
  unsigned short* w3l = (unsigned short*)alloc(8192 * 2);

  hipMemsetAsync(cnt, 0, (size_t)N * 4, stream);
  hipMemsetAsync(minenc, 0xFF, 64 * 4, stream);  // encoded +max

  int nb = (N + 1023) / 1024;
  k_prepw<<<160, 256, 0, stream>>>(W1, W2, W3, w1h, w1l, w2h, w2l, w3h, w3l);
  k_count<<<1024, 256, 0, stream>>>(edge, E, N, cnt);
  k_scan1<<<nb, 1024, 0, stream>>>(cnt, N, incl, bsum);
  k_scan2<<<1, 128, 0, stream>>>(bsum, nb, boff);
  k_aux<<<(N + 256) / 256, 256, 0, stream>>>(cnt, incl, boff, N, E, row_ptr, cursor, dinv);
  k_fill<<<1024, 256, 0, stream>>>(edge, E, N, cursor, srcs);

  int gx = (N + 63) / 64;
  int groups = (N + 31) / 32;
  // layer 1
  k_gemm_mfma<8><<<gx, 256, 0, stream>>>(X, w1h, w1l, dinv, P, N);
  k_agg2<128, 1><<<groups * 8, 256, 0, stream>>>(P, row_ptr, srcs, dinv, b1, H, N);
  // layer 2
  k_gemm_mfma<8><<<gx, 256, 0, stream>>>(H, w2h, w2l, dinv, P, N);
  k_agg2<128, 1><<<groups * 8, 256, 0, stream>>>(P, row_ptr, srcs, dinv, b2, H, N);
  // layer 3 (64 ch, no relu)
  k_gemm_mfma<4><<<gx, 256, 0, stream>>>(H, w3h, w3l, dinv, P, N);
  k_agg2<64, 0><<<groups * 4, 256, 0, stream>>>(P, row_ptr, srcs, dinv, b3, H, N);
  // min pool -> out[64]
  k_minpool<<<512, 256, 0, stream>>>(H, N, minenc);
  k_decode<<<1, 64, 0, stream>>>(minenc, out);
}

// Round 6
// 531.929 us; speedup vs baseline: 1.2224x; 1.2224x over previous
//
#include <hip/hip_runtime.h>
#include <stdint.h>
#include <stddef.h>

typedef short bf16x8 __attribute__((ext_vector_type(8)));
typedef float f32x4 __attribute__((ext_vector_type(4)));

// ---------------- helpers ----------------
static __device__ __forceinline__ unsigned enc_min(float v) {
  unsigned u = __float_as_uint(v);
  return (u & 0x80000000u) ? ~u : (u | 0x80000000u);
}
static __device__ __forceinline__ unsigned short f2bf(float f) {
  unsigned u = __float_as_uint(f);
  u += 0x7fffu + ((u >> 16) & 1u);
  return (unsigned short)(u >> 16);
}
static __device__ __forceinline__ float bf2f(unsigned short b) {
  return __uint_as_float(((unsigned)b) << 16);
}

// ---------------- degree count, XCD-binned ----------------
__global__ void k_count(const int* __restrict__ edge, int E, int N, int* __restrict__ cnt) {
  int grp = blockIdx.x & 7;
  int bslot = blockIdx.x >> 3;
  int nslot = gridDim.x >> 3;
  int lo = (int)(((long long)N * grp) >> 3);
  int hi = (int)(((long long)N * (grp + 1)) >> 3);
  for (int e = bslot * blockDim.x + threadIdx.x; e < E; e += nslot * blockDim.x) {
    int d = edge[E + e];
    if (d >= lo && d < hi) atomicAdd(&cnt[d], 1);
  }
}

// ---------------- block inclusive scan (1024/block) ----------------
__global__ void k_scan1(const int* __restrict__ cnt, int N,
                        int* __restrict__ incl, int* __restrict__ bsum) {
  __shared__ int sm[1024];
  int tid = threadIdx.x;
  int i = blockIdx.x * 1024 + tid;
  int v = (i < N) ? cnt[i] : 0;
  sm[tid] = v;
  __syncthreads();
  for (int off = 1; off < 1024; off <<= 1) {
    int t = (tid >= off) ? sm[tid - off] : 0;
    __syncthreads();
    sm[tid] += t;
    __syncthreads();
  }
  if (i < N) incl[i] = sm[tid];
  if (tid == 1023) bsum[blockIdx.x] = sm[1023];
}

// ---------------- scan of block sums (nb <= 128) ----------------
__global__ void k_scan2(const int* __restrict__ bsum, int nb, int* __restrict__ boff) {
  __shared__ int sm[128];
  int tid = threadIdx.x;
  int v = (tid < nb) ? bsum[tid] : 0;
  sm[tid] = v;
  __syncthreads();
  for (int off = 1; off < 128; off <<= 1) {
    int t = (tid >= off) ? sm[tid - off] : 0;
    __syncthreads();
    sm[tid] += t;
    __syncthreads();
  }
  if (tid < nb) boff[tid] = sm[tid] - v;  // exclusive
}

// ---------------- row_ptr / cursor / dinv ----------------
__global__ void k_aux(const int* __restrict__ cnt, const int* __restrict__ incl,
                      const int* __restrict__ boff, int N, int E,
                      int* __restrict__ row_ptr, int* __restrict__ cursor,
                      float* __restrict__ dinv) {
  int i = blockIdx.x * blockDim.x + threadIdx.x;
  if (i < N) {
    int rp = incl[i] - cnt[i] + boff[i >> 10];
    row_ptr[i] = rp;
    cursor[i] = rp;
    dinv[i] = 1.0f / sqrtf((float)(cnt[i] + 1));  // +1 self-loop
  } else if (i == N) {
    row_ptr[N] = E;
  }
}

// ---------------- CSR fill (bucket by dst, store src), XCD-binned ----------------
__global__ void k_fill(const int* __restrict__ edge, int E, int N,
                       int* __restrict__ cursor, int* __restrict__ srcs) {
  int grp = blockIdx.x & 7;
  int bslot = blockIdx.x >> 3;
  int nslot = gridDim.x >> 3;
  int lo = (int)(((long long)N * grp) >> 3);
  int hi = (int)(((long long)N * (grp + 1)) >> 3);
  for (int e = bslot * blockDim.x + threadIdx.x; e < E; e += nslot * blockDim.x) {
    int d = edge[E + e];
    if (d >= lo && d < hi) {
      int s = edge[e];
      int pos = atomicAdd(&cursor[d], 1);
      srcs[pos] = s;
    }
  }
}

// ---------------- weight prep: W[k][n] fp32 -> lane-ordered bf16 hi/lo fragments -----
// Fragment layout (per mfma_f32_16x16x32_bf16 B-operand, m89-verified):
//   element (n,k): nf=n>>4, mloc=n&15, kci=k>>5, quad=(k>>3)&3, j=k&7, lane=quad*16+mloc
//   out[(((nf*4+kci)*64 + lane)*8 + j]  -> a wave's fragment load is 1 KB contiguous.
__global__ void k_prepw(const float* __restrict__ W1, const float* __restrict__ W2,
                        const float* __restrict__ W3,
                        unsigned short* __restrict__ w1h, unsigned short* __restrict__ w1l,
                        unsigned short* __restrict__ w2h, unsigned short* __restrict__ w2l,
                        unsigned short* __restrict__ w3h, unsigned short* __restrict__ w3l) {
  const int K = 128;
  int idx = blockIdx.x * 256 + threadIdx.x;
  const float* W;
  unsigned short *oh, *ol;
  int Nn, base;
  if (idx < 16384) { W = W1; Nn = 128; oh = w1h; ol = w1l; base = idx; }
  else if (idx < 32768) { W = W2; Nn = 128; oh = w2h; ol = w2l; base = idx - 16384; }
  else if (idx < 40960) { W = W3; Nn = 64; oh = w3h; ol = w3l; base = idx - 32768; }
  else return;
  int n = base / K, k = base % K;
  float w = W[(size_t)k * Nn + n];
  unsigned short h = f2bf(w);
  unsigned short l = f2bf(w - bf2f(h));
  int nf = n >> 4, mloc = n & 15, kci = k >> 5, quad = (k >> 3) & 3, j = k & 7;
  size_t o = ((size_t)((nf * 4 + kci) * 64 + quad * 16 + mloc)) * 8 + j;
  oh[o] = h;
  ol[o] = l;
}

// ---------------- MFMA GEMM: P = bf16((A @ W) * dinv[row]), sliced layout ----------------
// bf16x3: D = Al*Bh + Ah*Bl + Ah*Bh (fp32 accum) -> ~fp32 accuracy.
// Block: 256 thr = 4 waves, tile 64 rows x (NFW*4*16) cols. Wave w owns column
// fragments nf = w*NFW..w*NFW+NFW-1 for ALL 64 rows: its W fragments (hi+lo,
// NFW*4*2 KB) are loaded ONCE into registers (coalesced 1 KB bursts), issued
// before the staging barrier so their latency overlaps A-staging. Inner loop
// is pure ds_read_b128 + MFMA (was: 400 MB/dispatch of scattered W re-reads).
template <int NFW>  // col-fragments per wave: 2 -> 128 cols, 1 -> 64 cols
__global__ __launch_bounds__(256) void k_gemm_mfma(const float* __restrict__ A,
                                                   const unsigned short* __restrict__ Wfh,
                                                   const unsigned short* __restrict__ Wfl,
                                                   const float* __restrict__ dinv,
                                                   unsigned short* __restrict__ P, int M) {
  const int K = 128;
  __shared__ unsigned short Ah[64][136];  // row stride 272 B, 16 B-aligned chunks
  __shared__ unsigned short Al[64][136];
  int tid = threadIdx.x;
  int m0 = blockIdx.x * 64;
  int w = tid >> 6, lane = tid & 63;

  // W fragments -> registers (coalesced; overlaps A staging below)
  bf16x8 bh[NFW][4], bl[NFW][4];
#pragma unroll
  for (int i = 0; i < NFW; ++i)
#pragma unroll
    for (int kci = 0; kci < 4; ++kci) {
      size_t o = ((size_t)(((w * NFW + i) * 4 + kci) * 64 + lane)) * 8;
      bh[i][kci] = *(const bf16x8*)&Wfh[o];
      bl[i][kci] = *(const bf16x8*)&Wfl[o];
    }

  // stage A tile (64 x 128 fp32) as bf16 hi/lo
#pragma unroll
  for (int q = 0; q < 8; ++q) {
    int f = q * 256 + tid;  // 0..2047 -> 64 rows x 32 float4
    int m = f >> 5, k4 = f & 31;
    int row = m0 + m;
    if (row >= M) row = M - 1;  // clamp; garbage rows never stored
    float4 v = *(const float4*)&A[(size_t)row * K + k4 * 4];
    unsigned short h0 = f2bf(v.x), h1 = f2bf(v.y), h2 = f2bf(v.z), h3 = f2bf(v.w);
    unsigned short l0 = f2bf(v.x - bf2f(h0)), l1 = f2bf(v.y - bf2f(h1));
    unsigned short l2 = f2bf(v.z - bf2f(h2)), l3 = f2bf(v.w - bf2f(h3));
    uint2 hh, ll;
    hh.x = (unsigned)h0 | ((unsigned)h1 << 16);
    hh.y = (unsigned)h2 | ((unsigned)h3 << 16);
    ll.x = (unsigned)l0 | ((unsigned)l1 << 16);
    ll.y = (unsigned)l2 | ((unsigned)l3 << 16);
    *(uint2*)&Ah[m][k4 * 4] = hh;
    *(uint2*)&Al[m][k4 * 4] = ll;
  }
  __syncthreads();

  int mloc = lane & 15, quad = lane >> 4;
  f32x4 acc[4][NFW];
#pragma unroll
  for (int rt = 0; rt < 4; ++rt)
#pragma unroll
    for (int i = 0; i < NFW; ++i) acc[rt][i] = (f32x4){0.f, 0.f, 0.f, 0.f};

#pragma unroll
  for (int rt = 0; rt < 4; ++rt) {
    const unsigned short* ph = &Ah[rt * 16 + mloc][quad * 8];
    const unsigned short* pl = &Al[rt * 16 + mloc][quad * 8];
#pragma unroll
    for (int kci = 0; kci < 4; ++kci) {
      bf16x8 ah = *(const bf16x8*)(ph + kci * 32);
      bf16x8 al = *(const bf16x8*)(pl + kci * 32);
#pragma unroll
      for (int i = 0; i < NFW; ++i) {
        acc[rt][i] = __builtin_amdgcn_mfma_f32_16x16x32_bf16(al, bh[i][kci], acc[rt][i], 0, 0, 0);
        acc[rt][i] = __builtin_amdgcn_mfma_f32_16x16x32_bf16(ah, bl[i][kci], acc[rt][i], 0, 0, 0);
        acc[rt][i] = __builtin_amdgcn_mfma_f32_16x16x32_bf16(ah, bh[i][kci], acc[rt][i], 0, 0, 0);
      }
    }
  }

  // epilogue: row = m0 + rt*16 + quad*4 + r, col = nf*16 + mloc; P sliced by nf
#pragma unroll
  for (int rt = 0; rt < 4; ++rt) {
    int rbase = m0 + rt * 16 + quad * 4;
#pragma unroll
    for (int r = 0; r < 4; ++r) {
      int row = rbase + r;
      if (row < M) {
        float dv = dinv[row];
#pragma unroll
        for (int i = 0; i < NFW; ++i) {
          int nf = w * NFW + i;
          P[(size_t)nf * M * 16 + (size_t)row * 16 + mloc] = f2bf(acc[rt][i][r] * dv);
        }
      }
    }
  }
}

// ---------------- sliced aggregation ----------------
// grid = ceil(N/32) * NS; blockIdx % NS = slice -> one XCD's L2 holds the
// 3.2 MB slice. Block: 256 thr = 4 waves; wave = 8 nodes x 8 ushort2 lanes.
template <int C, int RELU>
__global__ __launch_bounds__(256) void k_agg2(const unsigned short* __restrict__ P,
                                              const int* __restrict__ row_ptr,
                                              const int* __restrict__ srcs,
                                              const float* __restrict__ dinv,
                                              const float* __restrict__ bias,
                                              float* __restrict__ Hout, int N) {
  const int NS = C / 16;
  const int CAP = 768;
  __shared__ int s_idx[CAP];
  __shared__ int s_rp[33];
  int tid = threadIdx.x;
  int grp = blockIdx.x / NS;
  int s = blockIdx.x % NS;
  const unsigned short* Ps = P + (size_t)s * N * 16;

  int base = grp * 32;
  if (tid < 33) {
    int node = base + tid;
    s_rp[tid] = row_ptr[node < N ? node : N];
  }
  __syncthreads();
  int e0 = s_rp[0], e1 = s_rp[32];

  int wv = tid >> 6, lane = tid & 63;
  int nb = wv * 8 + (lane >> 3);
  int cp = lane & 7;
  int d = base + nb;
  bool valid = d < N;
  int lo_n = s_rp[nb], hi_n = s_rp[nb + 1];

  float a0 = 0.f, a1 = 0.f;
  if (valid) {
    unsigned v = *(const unsigned*)&Ps[(size_t)d * 16 + cp * 2];
    a0 = __uint_as_float(v << 16);
    a1 = __uint_as_float(v & 0xffff0000u);
  }

  for (int w0 = e0; w0 < e1; w0 += CAP) {
    int wend = min(w0 + CAP, e1);
    int cnt = wend - w0;
    __syncthreads();
    for (int t = tid; t < cnt; t += 256) s_idx[t] = srcs[w0 + t];
    __syncthreads();
    int lo = max(lo_n, w0), hi = min(hi_n, wend);
    int j = lo;
    for (; j + 4 <= hi; j += 4) {
      int i0 = s_idx[j - w0 + 0], i1 = s_idx[j - w0 + 1];
      int i2 = s_idx[j - w0 + 2], i3 = s_idx[j - w0 + 3];
      unsigned v0 = *(const unsigned*)&Ps[(size_t)i0 * 16 + cp * 2];
      unsigned v1 = *(const unsigned*)&Ps[(size_t)i1 * 16 + cp * 2];
      unsigned v2 = *(const unsigned*)&Ps[(size_t)i2 * 16 + cp * 2];
      unsigned v3 = *(const unsigned*)&Ps[(size_t)i3 * 16 + cp * 2];
      a0 += __uint_as_float(v0 << 16); a1 += __uint_as_float(v0 & 0xffff0000u);
      a0 += __uint_as_float(v1 << 16); a1 += __uint_as_float(v1 & 0xffff0000u);
      a0 += __uint_as_float(v2 << 16); a1 += __uint_as_float(v2 & 0xffff0000u);
      a0 += __uint_as_float(v3 << 16); a1 += __uint_as_float(v3 & 0xffff0000u);
    }
    for (; j < hi; ++j) {
      int i0 = s_idx[j - w0];
      unsigned v0 = *(const unsigned*)&Ps[(size_t)i0 * 16 + cp * 2];
      a0 += __uint_as_float(v0 << 16);
      a1 += __uint_as_float(v0 & 0xffff0000u);
    }
  }

  if (valid) {
    int c = s * 16 + cp * 2;
    float dvv = dinv[d];
    float h0 = dvv * a0 + bias[c];
    float h1 = dvv * a1 + bias[c + 1];
    if (RELU) { h0 = fmaxf(h0, 0.f); h1 = fmaxf(h1, 0.f); }
    *(float2*)&Hout[(size_t)d * C + c] = make_float2(h0, h1);
  }
}

// ---------------- min pool over nodes ----------------
__global__ void k_minpool(const float* __restrict__ H, int N, unsigned* __restrict__ minenc) {
  __shared__ float sm[256];
  int tid = threadIdx.x;
  int c = tid & 63;
  int r = (blockIdx.x * blockDim.x + tid) >> 6;
  int stride = (gridDim.x * blockDim.x) >> 6;
  float mn = 3.402823466e38f;
  for (; r < N; r += stride) mn = fminf(mn, H[(size_t)r * 64 + c]);
  sm[tid] = mn;
  __syncthreads();
  if (tid < 64) {
    mn = fminf(fminf(sm[tid], sm[tid + 64]), fminf(sm[tid + 128], sm[tid + 192]));
    atomicMin(&minenc[c], enc_min(mn));
  }
}

__global__ void k_decode(const unsigned* __restrict__ minenc, float* __restrict__ out) {
  int c = threadIdx.x;
  unsigned k = minenc[c];
  unsigned u = (k & 0x80000000u) ? (k & 0x7FFFFFFFu) : ~k;
  out[c] = __uint_as_float(u);
}

// ---------------- launch ----------------
extern "C" void kernel_launch(void* const* d_in, const int* in_sizes, int n_in,
                              void* d_out, int out_size, void* d_ws, size_t ws_size,
                              hipStream_t stream) {
  const float* X  = (const float*)d_in[0];
  const int* edge = (const int*)d_in[1];
  const float* W1 = (const float*)d_in[2];
  const float* b1 = (const float*)d_in[3];
  const float* W2 = (const float*)d_in[4];
  const float* b2 = (const float*)d_in[5];
  const float* W3 = (const float*)d_in[6];
  const float* b3 = (const float*)d_in[7];
  float* out = (float*)d_out;

  const int IN_CH = 128;
  int N = in_sizes[0] / IN_CH;
  int E = in_sizes[1] / 2;

  char* ws = (char*)d_ws;
  size_t off = 0;
  auto alloc = [&](size_t bytes) {
    void* p = ws + off;
    off = (off + bytes + 255) & ~(size_t)255;
    return p;
  };
  unsigned short* P = (unsigned short*)alloc((size_t)N * 128 * 2);  // 25.6 MB bf16, sliced
  float* H       = (float*)alloc((size_t)N * 128 * 4);              // 51.2 MB
  int* srcs      = (int*)alloc((size_t)E * 4);                      // 6.4 MB
  int* cnt       = (int*)alloc((size_t)N * 4);
  int* incl      = (int*)alloc((size_t)N * 4);
  int* row_ptr   = (int*)alloc((size_t)(N + 1) * 4);
  int* cursor    = (int*)alloc((size_t)N * 4);
  float* dinv    = (float*)alloc((size_t)N * 4);
  int* bsum      = (int*)alloc(1024);
  int* boff      = (int*)alloc(1024);
  unsigned* minenc = (unsigned*)alloc(256);
  unsigned short* w1h = (unsigned short*)alloc(16384 * 2);
  unsigned short* w1l = (unsigned short*)alloc(16384 * 2);
  unsigned short* w2h = (unsigned short*)alloc(16384 * 2);
  unsigned short* w2l = (unsigned short*)alloc(16384 * 2);
  unsigned short* w3h = (unsigned short*)alloc(8192 * 2);
  unsigned short* w3l = (unsigned short*)alloc(8192 * 2);

  hipMemsetAsync(cnt, 0, (size_t)N * 4, stream);
  hipMemsetAsync(minenc, 0xFF, 64 * 4, stream);  // encoded +max

  int nb = (N + 1023) / 1024;
  k_prepw<<<160, 256, 0, stream>>>(W1, W2, W3, w1h, w1l, w2h, w2l, w3h, w3l);
  k_count<<<1024, 256, 0, stream>>>(edge, E, N, cnt);
  k_scan1<<<nb, 1024, 0, stream>>>(cnt, N, incl, bsum);
  k_scan2<<<1, 128, 0, stream>>>(bsum, nb, boff);
  k_aux<<<(N + 256) / 256, 256, 0, stream>>>(cnt, incl, boff, N, E, row_ptr, cursor, dinv);
  k_fill<<<1024, 256, 0, stream>>>(edge, E, N, cursor, srcs);

  int gx = (N + 63) / 64;
  int groups = (N + 31) / 32;
  // layer 1
  k_gemm_mfma<2><<<gx, 256, 0, stream>>>(X, w1h, w1l, dinv, P, N);
  k_agg2<128, 1><<<groups * 8, 256, 0, stream>>>(P, row_ptr, srcs, dinv, b1, H, N);
  // layer 2
  k_gemm_mfma<2><<<gx, 256, 0, stream>>>(H, w2h, w2l, dinv, P, N);
  k_agg2<128, 1><<<groups * 8, 256, 0, stream>>>(P, row_ptr, srcs, dinv, b2, H, N);
  // layer 3 (64 ch, no relu)
  k_gemm_mfma<1><<<gx, 256, 0, stream>>>(H, w3h, w3l, dinv, P, N);
  k_agg2<64, 0><<<groups * 4, 256, 0, stream>>>(P, row_ptr, srcs, dinv, b3, H, N);
  // min pool -> out[64]
  k_minpool<<<512, 256, 0, stream>>>(H, N, minenc);
  k_decode<<<1, 64, 0, stream>>>(minenc, out);
}

// Round 7
// 504.882 us; speedup vs baseline: 1.2879x; 1.0536x over previous
//
#include <hip/hip_runtime.h>
#include <stdint.h>
#include <stddef.h>
#include <float.h>

typedef short bf16x8 __attribute__((ext_vector_type(8)));
typedef float f32x4 __attribute__((ext_vector_type(4)));

// ---------------- helpers ----------------
static __device__ __forceinline__ unsigned enc_min(float v) {
  unsigned u = __float_as_uint(v);
  return (u & 0x80000000u) ? ~u : (u | 0x80000000u);
}
static __device__ __forceinline__ unsigned short f2bf(float f) {
  unsigned u = __float_as_uint(f);
  u += 0x7fffu + ((u >> 16) & 1u);
  return (unsigned short)(u >> 16);
}
static __device__ __forceinline__ float bf2f(unsigned short b) {
  return __uint_as_float(((unsigned)b) << 16);
}
// unpack 8 bf16 (4 dwords) and accumulate into 8 fp32 channels.
// lo channel: <<16 (1 op); hi channel: mask (1 op); + add = 2 VALU/element.
static __device__ __forceinline__ void acc8(float* a, uint4 v) {
  a[0] += __uint_as_float(v.x << 16);
  a[1] += __uint_as_float(v.x & 0xffff0000u);
  a[2] += __uint_as_float(v.y << 16);
  a[3] += __uint_as_float(v.y & 0xffff0000u);
  a[4] += __uint_as_float(v.z << 16);
  a[5] += __uint_as_float(v.z & 0xffff0000u);
  a[6] += __uint_as_float(v.w << 16);
  a[7] += __uint_as_float(v.w & 0xffff0000u);
}

// ---------------- degree count, XCD-binned ----------------
__global__ void k_count(const int* __restrict__ edge, int E, int N, int* __restrict__ cnt) {
  int grp = blockIdx.x & 7;
  int bslot = blockIdx.x >> 3;
  int nslot = gridDim.x >> 3;
  int lo = (int)(((long long)N * grp) >> 3);
  int hi = (int)(((long long)N * (grp + 1)) >> 3);
  for (int e = bslot * blockDim.x + threadIdx.x; e < E; e += nslot * blockDim.x) {
    int d = edge[E + e];
    if (d >= lo && d < hi) atomicAdd(&cnt[d], 1);
  }
}

// ---------------- block inclusive scan (1024/block) ----------------
__global__ void k_scan1(const int* __restrict__ cnt, int N,
                        int* __restrict__ incl, int* __restrict__ bsum) {
  __shared__ int sm[1024];
  int tid = threadIdx.x;
  int i = blockIdx.x * 1024 + tid;
  int v = (i < N) ? cnt[i] : 0;
  sm[tid] = v;
  __syncthreads();
  for (int off = 1; off < 1024; off <<= 1) {
    int t = (tid >= off) ? sm[tid - off] : 0;
    __syncthreads();
    sm[tid] += t;
    __syncthreads();
  }
  if (i < N) incl[i] = sm[tid];
  if (tid == 1023) bsum[blockIdx.x] = sm[1023];
}

// ---------------- scan of block sums (nb <= 128) ----------------
__global__ void k_scan2(const int* __restrict__ bsum, int nb, int* __restrict__ boff) {
  __shared__ int sm[128];
  int tid = threadIdx.x;
  int v = (tid < nb) ? bsum[tid] : 0;
  sm[tid] = v;
  __syncthreads();
  for (int off = 1; off < 128; off <<= 1) {
    int t = (tid >= off) ? sm[tid - off] : 0;
    __syncthreads();
    sm[tid] += t;
    __syncthreads();
  }
  if (tid < nb) boff[tid] = sm[tid] - v;  // exclusive
}

// ---------------- row_ptr / cursor / dinv ----------------
__global__ void k_aux(const int* __restrict__ cnt, const int* __restrict__ incl,
                      const int* __restrict__ boff, int N, int E,
                      int* __restrict__ row_ptr, int* __restrict__ cursor,
                      float* __restrict__ dinv) {
  int i = blockIdx.x * blockDim.x + threadIdx.x;
  if (i < N) {
    int rp = incl[i] - cnt[i] + boff[i >> 10];
    row_ptr[i] = rp;
    cursor[i] = rp;
    dinv[i] = 1.0f / sqrtf((float)(cnt[i] + 1));  // +1 self-loop
  } else if (i == N) {
    row_ptr[N] = E;
  }
}

// ---------------- CSR fill (bucket by dst, store src), XCD-binned ----------------
__global__ void k_fill(const int* __restrict__ edge, int E, int N,
                       int* __restrict__ cursor, int* __restrict__ srcs) {
  int grp = blockIdx.x & 7;
  int bslot = blockIdx.x >> 3;
  int nslot = gridDim.x >> 3;
  int lo = (int)(((long long)N * grp) >> 3);
  int hi = (int)(((long long)N * (grp + 1)) >> 3);
  for (int e = bslot * blockDim.x + threadIdx.x; e < E; e += nslot * blockDim.x) {
    int d = edge[E + e];
    if (d >= lo && d < hi) {
      int s = edge[e];
      int pos = atomicAdd(&cursor[d], 1);
      srcs[pos] = s;
    }
  }
}

// ---------------- weight prep: W[k][n] fp32 -> lane-ordered bf16 hi/lo fragments -----
__global__ void k_prepw(const float* __restrict__ W1, const float* __restrict__ W2,
                        const float* __restrict__ W3,
                        unsigned short* __restrict__ w1h, unsigned short* __restrict__ w1l,
                        unsigned short* __restrict__ w2h, unsigned short* __restrict__ w2l,
                        unsigned short* __restrict__ w3h, unsigned short* __restrict__ w3l) {
  const int K = 128;
  int idx = blockIdx.x * 256 + threadIdx.x;
  const float* W;
  unsigned short *oh, *ol;
  int Nn, base;
  if (idx < 16384) { W = W1; Nn = 128; oh = w1h; ol = w1l; base = idx; }
  else if (idx < 32768) { W = W2; Nn = 128; oh = w2h; ol = w2l; base = idx - 16384; }
  else if (idx < 40960) { W = W3; Nn = 64; oh = w3h; ol = w3l; base = idx - 32768; }
  else return;
  int n = base / K, k = base % K;
  float w = W[(size_t)k * Nn + n];
  unsigned short h = f2bf(w);
  unsigned short l = f2bf(w - bf2f(h));
  int nf = n >> 4, mloc = n & 15, kci = k >> 5, quad = (k >> 3) & 3, j = k & 7;
  size_t o = ((size_t)((nf * 4 + kci) * 64 + quad * 16 + mloc)) * 8 + j;
  oh[o] = h;
  ol[o] = l;
}

// ---------------- MFMA GEMM: P = bf16((A @ W) * dinv[row]), sliced layout ----------------
// bf16x3: D = Al*Bh + Ah*Bl + Ah*Bh (fp32 accum) -> ~fp32 accuracy.
template <int NFW>  // col-fragments per wave: 2 -> 128 cols, 1 -> 64 cols
__global__ __launch_bounds__(256) void k_gemm_mfma(const float* __restrict__ A,
                                                   const unsigned short* __restrict__ Wfh,
                                                   const unsigned short* __restrict__ Wfl,
                                                   const float* __restrict__ dinv,
                                                   unsigned short* __restrict__ P, int M) {
  const int K = 128;
  __shared__ unsigned short Ah[64][136];
  __shared__ unsigned short Al[64][136];
  int tid = threadIdx.x;
  int m0 = blockIdx.x * 64;
  int w = tid >> 6, lane = tid & 63;

  // W fragments -> registers (coalesced; overlaps A staging below)
  bf16x8 bh[NFW][4], bl[NFW][4];
#pragma unroll
  for (int i = 0; i < NFW; ++i)
#pragma unroll
    for (int kci = 0; kci < 4; ++kci) {
      size_t o = ((size_t)(((w * NFW + i) * 4 + kci) * 64 + lane)) * 8;
      bh[i][kci] = *(const bf16x8*)&Wfh[o];
      bl[i][kci] = *(const bf16x8*)&Wfl[o];
    }

  // stage A tile (64 x 128 fp32) as bf16 hi/lo
#pragma unroll
  for (int q = 0; q < 8; ++q) {
    int f = q * 256 + tid;
    int m = f >> 5, k4 = f & 31;
    int row = m0 + m;
    if (row >= M) row = M - 1;
    float4 v = *(const float4*)&A[(size_t)row * K + k4 * 4];
    unsigned short h0 = f2bf(v.x), h1 = f2bf(v.y), h2 = f2bf(v.z), h3 = f2bf(v.w);
    unsigned short l0 = f2bf(v.x - bf2f(h0)), l1 = f2bf(v.y - bf2f(h1));
    unsigned short l2 = f2bf(v.z - bf2f(h2)), l3 = f2bf(v.w - bf2f(h3));
    uint2 hh, ll;
    hh.x = (unsigned)h0 | ((unsigned)h1 << 16);
    hh.y = (unsigned)h2 | ((unsigned)h3 << 16);
    ll.x = (unsigned)l0 | ((unsigned)l1 << 16);
    ll.y = (unsigned)l2 | ((unsigned)l3 << 16);
    *(uint2*)&Ah[m][k4 * 4] = hh;
    *(uint2*)&Al[m][k4 * 4] = ll;
  }
  __syncthreads();

  int mloc = lane & 15, quad = lane >> 4;
  f32x4 acc[4][NFW];
#pragma unroll
  for (int rt = 0; rt < 4; ++rt)
#pragma unroll
    for (int i = 0; i < NFW; ++i) acc[rt][i] = (f32x4){0.f, 0.f, 0.f, 0.f};

#pragma unroll
  for (int rt = 0; rt < 4; ++rt) {
    const unsigned short* ph = &Ah[rt * 16 + mloc][quad * 8];
    const unsigned short* pl = &Al[rt * 16 + mloc][quad * 8];
#pragma unroll
    for (int kci = 0; kci < 4; ++kci) {
      bf16x8 ah = *(const bf16x8*)(ph + kci * 32);
      bf16x8 al = *(const bf16x8*)(pl + kci * 32);
#pragma unroll
      for (int i = 0; i < NFW; ++i) {
        acc[rt][i] = __builtin_amdgcn_mfma_f32_16x16x32_bf16(al, bh[i][kci], acc[rt][i], 0, 0, 0);
        acc[rt][i] = __builtin_amdgcn_mfma_f32_16x16x32_bf16(ah, bl[i][kci], acc[rt][i], 0, 0, 0);
        acc[rt][i] = __builtin_amdgcn_mfma_f32_16x16x32_bf16(ah, bh[i][kci], acc[rt][i], 0, 0, 0);
      }
    }
  }

#pragma unroll
  for (int rt = 0; rt < 4; ++rt) {
    int rbase = m0 + rt * 16 + quad * 4;
#pragma unroll
    for (int r = 0; r < 4; ++r) {
      int row = rbase + r;
      if (row < M) {
        float dv = dinv[row];
#pragma unroll
        for (int i = 0; i < NFW; ++i) {
          int nf = w * NFW + i;
          P[(size_t)nf * M * 16 + (size_t)row * 16 + mloc] = f2bf(acc[rt][i][r] * dv);
        }
      }
    }
  }
}

// ---------------- wave-autonomous sliced aggregation ----------------
// grid = ceil(groups/4) * NS; blockIdx % NS = slice (XCD-resident, 3.2 MB).
// Block = 4 waves; EACH WAVE owns one 32-node group with a private LDS edge
// window (no __syncthreads in the hot loop — wave-lockstep LDS).
// Wave lane map: nb = lane>>1 (node 0..31), cp = lane&1 (16B half of the
// 32B row) -> one dwordx4 gather covers 8 channels; 32-bit saddr offsets.
// Accumulation order per (node,channel) identical to previous rounds
// (self-loop, then edges ascending) -> bitwise-identical output.
// POOL: fuse min-pool: shfl_xor parity reduction + atomicMin per block.
template <int C, int RELU, int POOL>
__global__ __launch_bounds__(256) void k_agg3(const unsigned short* __restrict__ P,
                                              const int* __restrict__ row_ptr,
                                              const int* __restrict__ srcs,
                                              const float* __restrict__ dinv,
                                              const float* __restrict__ bias,
                                              float* __restrict__ Hout,
                                              unsigned* __restrict__ minenc, int N) {
  const int NS = C / 16;
  const int CAP = 768;  // group mean 512 edges, sigma ~23 -> 1 window whp
  __shared__ int s_idx[4][CAP];
  __shared__ float s_red[4][16];
  int tid = threadIdx.x;
  int wv = tid >> 6, lane = tid & 63;
  int s = blockIdx.x % NS;
  int gbase = (blockIdx.x / NS) * 4 + wv;  // this wave's 32-node group
  const char* Pb = (const char*)(P + (size_t)s * N * 16);

  int nb = lane >> 1, cp = lane & 1;
  int cp16 = cp * 16;
  int d = gbase * 32 + nb;
  int dc = d < N ? d : N - 1;
  bool valid = d < N;

  int gfirst = gbase * 32;
  int e0 = row_ptr[gfirst < N ? gfirst : N];
  int e1 = row_ptr[(gfirst + 32) < N ? (gfirst + 32) : N];
  int lo_n = row_ptr[d < N ? d : N];
  int hi_n = row_ptr[(d + 1) < N ? (d + 1) : N];

  float a[8];
  {  // self-loop term (clamped row for invalid lanes; never stored)
    uint4 v = *(const uint4*)(Pb + ((unsigned)dc * 32u + (unsigned)cp16));
    a[0] = __uint_as_float(v.x << 16);
    a[1] = __uint_as_float(v.x & 0xffff0000u);
    a[2] = __uint_as_float(v.y << 16);
    a[3] = __uint_as_float(v.y & 0xffff0000u);
    a[4] = __uint_as_float(v.z << 16);
    a[5] = __uint_as_float(v.z & 0xffff0000u);
    a[6] = __uint_as_float(v.w << 16);
    a[7] = __uint_as_float(v.w & 0xffff0000u);
  }

  for (int w0 = e0; w0 < e1; w0 += CAP) {
    int wend = min(w0 + CAP, e1);
    int cnt = wend - w0;
    __builtin_amdgcn_wave_barrier();
    for (int t = lane; t < cnt; t += 64) s_idx[wv][t] = srcs[w0 + t];
    __builtin_amdgcn_wave_barrier();
    int j = max(lo_n, w0), hi = min(hi_n, wend);
    for (; j + 2 <= hi; j += 2) {
      unsigned i0 = (unsigned)s_idx[wv][j - w0];
      unsigned i1 = (unsigned)s_idx[wv][j - w0 + 1];
      uint4 v0 = *(const uint4*)(Pb + (i0 * 32u + (unsigned)cp16));
      uint4 v1 = *(const uint4*)(Pb + (i1 * 32u + (unsigned)cp16));
      acc8(a, v0);
      acc8(a, v1);
    }
    if (j < hi) {
      unsigned i0 = (unsigned)s_idx[wv][j - w0];
      uint4 v0 = *(const uint4*)(Pb + (i0 * 32u + (unsigned)cp16));
      acc8(a, v0);
    }
  }

  int c0 = s * 16 + cp * 8;
  float dv = dinv[dc];
  float4 bv0 = *(const float4*)&bias[c0];
  float4 bv1 = *(const float4*)&bias[c0 + 4];
  float h[8];
  h[0] = dv * a[0] + bv0.x; h[1] = dv * a[1] + bv0.y;
  h[2] = dv * a[2] + bv0.z; h[3] = dv * a[3] + bv0.w;
  h[4] = dv * a[4] + bv1.x; h[5] = dv * a[5] + bv1.y;
  h[6] = dv * a[6] + bv1.z; h[7] = dv * a[7] + bv1.w;
  if (RELU) {
#pragma unroll
    for (int k = 0; k < 8; ++k) h[k] = fmaxf(h[k], 0.f);
  }

  if (POOL) {
    if (!valid) {
#pragma unroll
      for (int k = 0; k < 8; ++k) h[k] = FLT_MAX;
    }
    // min over the wave's 32 nodes: xor strides 2..32 preserve lane parity (cp)
#pragma unroll
    for (int off = 2; off < 64; off <<= 1) {
#pragma unroll
      for (int k = 0; k < 8; ++k) h[k] = fminf(h[k], __shfl_xor(h[k], off, 64));
    }
    if (lane < 2) {
#pragma unroll
      for (int k = 0; k < 8; ++k) s_red[wv][cp * 8 + k] = h[k];
    }
    __syncthreads();
    if (tid < 16) {
      float m = fminf(fminf(s_red[0][tid], s_red[1][tid]),
                      fminf(s_red[2][tid], s_red[3][tid]));
      atomicMin(&minenc[s * 16 + tid], enc_min(m));
    }
  } else if (valid) {
    float4 o0 = make_float4(h[0], h[1], h[2], h[3]);
    float4 o1 = make_float4(h[4], h[5], h[6], h[7]);
    *(float4*)&Hout[(size_t)d * C + c0] = o0;
    *(float4*)&Hout[(size_t)d * C + c0 + 4] = o1;
  }
}

__global__ void k_decode(const unsigned* __restrict__ minenc, float* __restrict__ out) {
  int c = threadIdx.x;
  unsigned k = minenc[c];
  unsigned u = (k & 0x80000000u) ? (k & 0x7FFFFFFFu) : ~k;
  out[c] = __uint_as_float(u);
}

// ---------------- launch ----------------
extern "C" void kernel_launch(void* const* d_in, const int* in_sizes, int n_in,
                              void* d_out, int out_size, void* d_ws, size_t ws_size,
                              hipStream_t stream) {
  const float* X  = (const float*)d_in[0];
  const int* edge = (const int*)d_in[1];
  const float* W1 = (const float*)d_in[2];
  const float* b1 = (const float*)d_in[3];
  const float* W2 = (const float*)d_in[4];
  const float* b2 = (const float*)d_in[5];
  const float* W3 = (const float*)d_in[6];
  const float* b3 = (const float*)d_in[7];
  float* out = (float*)d_out;

  const int IN_CH = 128;
  int N = in_sizes[0] / IN_CH;
  int E = in_sizes[1] / 2;

  char* ws = (char*)d_ws;
  size_t off = 0;
  auto alloc = [&](size_t bytes) {
    void* p = ws + off;
    off = (off + bytes + 255) & ~(size_t)255;
    return p;
  };
  unsigned short* P = (unsigned short*)alloc((size_t)N * 128 * 2);  // 25.6 MB bf16, sliced
  float* H       = (float*)alloc((size_t)N * 128 * 4);              // 51.2 MB
  int* srcs      = (int*)alloc((size_t)E * 4);                      // 6.4 MB
  int* cnt       = (int*)alloc((size_t)N * 4);
  int* incl      = (int*)alloc((size_t)N * 4);
  int* row_ptr   = (int*)alloc((size_t)(N + 1) * 4);
  int* cursor    = (int*)alloc((size_t)N * 4);
  float* dinv    = (float*)alloc((size_t)N * 4);
  int* bsum      = (int*)alloc(1024);
  int* boff      = (int*)alloc(1024);
  unsigned* minenc = (unsigned*)alloc(256);
  unsigned short* w1h = (unsigned short*)alloc(16384 * 2);
  unsigned short* w1l = (unsigned short*)alloc(16384 * 2);
  unsigned short* w2h = (unsigned short*)alloc(16384 * 2);
  unsigned short* w2l = (unsigned short*)alloc(16384 * 2);
  unsigned short* w3h = (unsigned short*)alloc(8192 * 2);
  unsigned short* w3l = (unsigned short*)alloc(8192 * 2);

  hipMemsetAsync(cnt, 0, (size_t)N * 4, stream);
  hipMemsetAsync(minenc, 0xFF, 64 * 4, stream);  // encoded +max

  int nb = (N + 1023) / 1024;
  k_prepw<<<160, 256, 0, stream>>>(W1, W2, W3, w1h, w1l, w2h, w2l, w3h, w3l);
  k_count<<<1024, 256, 0, stream>>>(edge, E, N, cnt);
  k_scan1<<<nb, 1024, 0, stream>>>(cnt, N, incl, bsum);
  k_scan2<<<1, 128, 0, stream>>>(bsum, nb, boff);
  k_aux<<<(N + 256) / 256, 256, 0, stream>>>(cnt, incl, boff, N, E, row_ptr, cursor, dinv);
  k_fill<<<1024, 256, 0, stream>>>(edge, E, N, cursor, srcs);

  int gx = (N + 63) / 64;
  int gblocks = (N + 127) / 128;  // 4 groups (32 nodes each) per block
  // layer 1
  k_gemm_mfma<2><<<gx, 256, 0, stream>>>(X, w1h, w1l, dinv, P, N);
  k_agg3<128, 1, 0><<<gblocks * 8, 256, 0, stream>>>(P, row_ptr, srcs, dinv, b1, H, minenc, N);
  // layer 2
  k_gemm_mfma<2><<<gx, 256, 0, stream>>>(H, w2h, w2l, dinv, P, N);
  k_agg3<128, 1, 0><<<gblocks * 8, 256, 0, stream>>>(P, row_ptr, srcs, dinv, b2, H, minenc, N);
  // layer 3 (64 ch, no relu) with fused min-pool
  k_gemm_mfma<1><<<gx, 256, 0, stream>>>(H, w3h, w3l, dinv, P, N);
  k_agg3<64, 0, 1><<<gblocks * 4, 256, 0, stream>>>(P, row_ptr, srcs, dinv, b3, nullptr, minenc, N);
  // decode encoded mins -> out[64]
  k_decode<<<1, 64, 0, stream>>>(minenc, out);
}

// Round 8
// 487.389 us; speedup vs baseline: 1.3342x; 1.0359x over previous
//
#include <hip/hip_runtime.h>
#include <stdint.h>
#include <stddef.h>
#include <float.h>

typedef short bf16x8 __attribute__((ext_vector_type(8)));
typedef float f32x4 __attribute__((ext_vector_type(4)));

// ---------------- helpers ----------------
static __device__ __forceinline__ unsigned enc_min(float v) {
  unsigned u = __float_as_uint(v);
  return (u & 0x80000000u) ? ~u : (u | 0x80000000u);
}
static __device__ __forceinline__ unsigned short f2bf(float f) {
  unsigned u = __float_as_uint(f);
  u += 0x7fffu + ((u >> 16) & 1u);
  return (unsigned short)(u >> 16);
}
static __device__ __forceinline__ float bf2f(unsigned short b) {
  return __uint_as_float(((unsigned)b) << 16);
}
static __device__ __forceinline__ void acc8(float* a, uint4 v) {
  a[0] += __uint_as_float(v.x << 16);
  a[1] += __uint_as_float(v.x & 0xffff0000u);
  a[2] += __uint_as_float(v.y << 16);
  a[3] += __uint_as_float(v.y & 0xffff0000u);
  a[4] += __uint_as_float(v.z << 16);
  a[5] += __uint_as_float(v.z & 0xffff0000u);
  a[6] += __uint_as_float(v.w << 16);
  a[7] += __uint_as_float(v.w & 0xffff0000u);
}

// ---------------- degree count, XCD-binned ----------------
__global__ void k_count(const int* __restrict__ edge, int E, int N, int* __restrict__ cnt) {
  int grp = blockIdx.x & 7;
  int bslot = blockIdx.x >> 3;
  int nslot = gridDim.x >> 3;
  int lo = (int)(((long long)N * grp) >> 3);
  int hi = (int)(((long long)N * (grp + 1)) >> 3);
  for (int e = bslot * blockDim.x + threadIdx.x; e < E; e += nslot * blockDim.x) {
    int d = edge[E + e];
    if (d >= lo && d < hi) atomicAdd(&cnt[d], 1);
  }
}

// ---------------- block inclusive scan (1024/block) ----------------
__global__ void k_scan1(const int* __restrict__ cnt, int N,
                        int* __restrict__ incl, int* __restrict__ bsum) {
  __shared__ int sm[1024];
  int tid = threadIdx.x;
  int i = blockIdx.x * 1024 + tid;
  int v = (i < N) ? cnt[i] : 0;
  sm[tid] = v;
  __syncthreads();
  for (int off = 1; off < 1024; off <<= 1) {
    int t = (tid >= off) ? sm[tid - off] : 0;
    __syncthreads();
    sm[tid] += t;
    __syncthreads();
  }
  if (i < N) incl[i] = sm[tid];
  if (tid == 1023) bsum[blockIdx.x] = sm[1023];
}

// ---------------- scan of block sums (nb <= 128) ----------------
__global__ void k_scan2(const int* __restrict__ bsum, int nb, int* __restrict__ boff) {
  __shared__ int sm[128];
  int tid = threadIdx.x;
  int v = (tid < nb) ? bsum[tid] : 0;
  sm[tid] = v;
  __syncthreads();
  for (int off = 1; off < 128; off <<= 1) {
    int t = (tid >= off) ? sm[tid - off] : 0;
    __syncthreads();
    sm[tid] += t;
    __syncthreads();
  }
  if (tid < nb) boff[tid] = sm[tid] - v;  // exclusive
}

// ---------------- row_ptr / cursor / dinv ----------------
__global__ void k_aux(const int* __restrict__ cnt, const int* __restrict__ incl,
                      const int* __restrict__ boff, int N, int E,
                      int* __restrict__ row_ptr, int* __restrict__ cursor,
                      float* __restrict__ dinv) {
  int i = blockIdx.x * blockDim.x + threadIdx.x;
  if (i < N) {
    int rp = incl[i] - cnt[i] + boff[i >> 10];
    row_ptr[i] = rp;
    cursor[i] = rp;
    dinv[i] = 1.0f / sqrtf((float)(cnt[i] + 1));  // +1 self-loop
  } else if (i == N) {
    row_ptr[N] = E;
  }
}

// ---------------- CSR fill (bucket by dst, store src), XCD-binned ----------------
__global__ void k_fill(const int* __restrict__ edge, int E, int N,
                       int* __restrict__ cursor, int* __restrict__ srcs) {
  int grp = blockIdx.x & 7;
  int bslot = blockIdx.x >> 3;
  int nslot = gridDim.x >> 3;
  int lo = (int)(((long long)N * grp) >> 3);
  int hi = (int)(((long long)N * (grp + 1)) >> 3);
  for (int e = bslot * blockDim.x + threadIdx.x; e < E; e += nslot * blockDim.x) {
    int d = edge[E + e];
    if (d >= lo && d < hi) {
      int s = edge[e];
      int pos = atomicAdd(&cursor[d], 1);
      srcs[pos] = s;
    }
  }
}

// ---------------- weight prep: W[k][n] fp32 -> lane-ordered bf16 hi/lo fragments -----
__global__ void k_prepw(const float* __restrict__ W1, const float* __restrict__ W2,
                        const float* __restrict__ W3,
                        unsigned short* __restrict__ w1h, unsigned short* __restrict__ w1l,
                        unsigned short* __restrict__ w2h, unsigned short* __restrict__ w2l,
                        unsigned short* __restrict__ w3h, unsigned short* __restrict__ w3l) {
  const int K = 128;
  int idx = blockIdx.x * 256 + threadIdx.x;
  const float* W;
  unsigned short *oh, *ol;
  int Nn, base;
  if (idx < 16384) { W = W1; Nn = 128; oh = w1h; ol = w1l; base = idx; }
  else if (idx < 32768) { W = W2; Nn = 128; oh = w2h; ol = w2l; base = idx - 16384; }
  else if (idx < 40960) { W = W3; Nn = 64; oh = w3h; ol = w3l; base = idx - 32768; }
  else return;
  int n = base / K, k = base % K;
  float w = W[(size_t)k * Nn + n];
  unsigned short h = f2bf(w);
  unsigned short l = f2bf(w - bf2f(h));
  int nf = n >> 4, mloc = n & 15, kci = k >> 5, quad = (k >> 3) & 3, j = k & 7;
  size_t o = ((size_t)((nf * 4 + kci) * 64 + quad * 16 + mloc)) * 8 + j;
  oh[o] = h;
  ol[o] = l;
}

// ---------------- MFMA GEMM: P = bf16((A @ W) * dinv[row]), 32ch-sliced layout -------
// bf16x3: D = Al*Bh + Ah*Bl + Ah*Bh (fp32 accum) -> ~fp32 accuracy.
// P layout: slice s (32 ch) contiguous; node row = 64 B (one full cache line):
//   P[s*M*32 + row*32 + (ch & 31)]
template <int NFW>  // col-fragments per wave: 2 -> 128 cols, 1 -> 64 cols
__global__ __launch_bounds__(256) void k_gemm_mfma(const float* __restrict__ A,
                                                   const unsigned short* __restrict__ Wfh,
                                                   const unsigned short* __restrict__ Wfl,
                                                   const float* __restrict__ dinv,
                                                   unsigned short* __restrict__ P, int M) {
  const int K = 128;
  __shared__ unsigned short Ah[64][136];
  __shared__ unsigned short Al[64][136];
  int tid = threadIdx.x;
  int m0 = blockIdx.x * 64;
  int w = tid >> 6, lane = tid & 63;

  // W fragments -> registers (coalesced; overlaps A staging below)
  bf16x8 bh[NFW][4], bl[NFW][4];
#pragma unroll
  for (int i = 0; i < NFW; ++i)
#pragma unroll
    for (int kci = 0; kci < 4; ++kci) {
      size_t o = ((size_t)(((w * NFW + i) * 4 + kci) * 64 + lane)) * 8;
      bh[i][kci] = *(const bf16x8*)&Wfh[o];
      bl[i][kci] = *(const bf16x8*)&Wfl[o];
    }

  // stage A tile (64 x 128 fp32) as bf16 hi/lo
#pragma unroll
  for (int q = 0; q < 8; ++q) {
    int f = q * 256 + tid;
    int m = f >> 5, k4 = f & 31;
    int row = m0 + m;
    if (row >= M) row = M - 1;
    float4 v = *(const float4*)&A[(size_t)row * K + k4 * 4];
    unsigned short h0 = f2bf(v.x), h1 = f2bf(v.y), h2 = f2bf(v.z), h3 = f2bf(v.w);
    unsigned short l0 = f2bf(v.x - bf2f(h0)), l1 = f2bf(v.y - bf2f(h1));
    unsigned short l2 = f2bf(v.z - bf2f(h2)), l3 = f2bf(v.w - bf2f(h3));
    uint2 hh, ll;
    hh.x = (unsigned)h0 | ((unsigned)h1 << 16);
    hh.y = (unsigned)h2 | ((unsigned)h3 << 16);
    ll.x = (unsigned)l0 | ((unsigned)l1 << 16);
    ll.y = (unsigned)l2 | ((unsigned)l3 << 16);
    *(uint2*)&Ah[m][k4 * 4] = hh;
    *(uint2*)&Al[m][k4 * 4] = ll;
  }
  __syncthreads();

  int mloc = lane & 15, quad = lane >> 4;
  f32x4 acc[4][NFW];
#pragma unroll
  for (int rt = 0; rt < 4; ++rt)
#pragma unroll
    for (int i = 0; i < NFW; ++i) acc[rt][i] = (f32x4){0.f, 0.f, 0.f, 0.f};

#pragma unroll
  for (int rt = 0; rt < 4; ++rt) {
    const unsigned short* ph = &Ah[rt * 16 + mloc][quad * 8];
    const unsigned short* pl = &Al[rt * 16 + mloc][quad * 8];
#pragma unroll
    for (int kci = 0; kci < 4; ++kci) {
      bf16x8 ah = *(const bf16x8*)(ph + kci * 32);
      bf16x8 al = *(const bf16x8*)(pl + kci * 32);
#pragma unroll
      for (int i = 0; i < NFW; ++i) {
        acc[rt][i] = __builtin_amdgcn_mfma_f32_16x16x32_bf16(al, bh[i][kci], acc[rt][i], 0, 0, 0);
        acc[rt][i] = __builtin_amdgcn_mfma_f32_16x16x32_bf16(ah, bl[i][kci], acc[rt][i], 0, 0, 0);
        acc[rt][i] = __builtin_amdgcn_mfma_f32_16x16x32_bf16(ah, bh[i][kci], acc[rt][i], 0, 0, 0);
      }
    }
  }

  // epilogue: row = m0 + rt*16 + quad*4 + r; col = nf*16 + mloc
  // 32ch-slice address: slice = nf>>1, within = (nf&1)*16 + mloc
#pragma unroll
  for (int rt = 0; rt < 4; ++rt) {
    int rbase = m0 + rt * 16 + quad * 4;
#pragma unroll
    for (int r = 0; r < 4; ++r) {
      int row = rbase + r;
      if (row < M) {
        float dv = dinv[row];
#pragma unroll
        for (int i = 0; i < NFW; ++i) {
          int nf = w * NFW + i;
          size_t o = (size_t)(nf >> 1) * M * 32 + (size_t)row * 32 + ((nf & 1) * 16 + mloc);
          P[o] = f2bf(acc[rt][i][r] * dv);
        }
      }
    }
  }
}

// ---------------- full-line sliced aggregation ----------------
// Slice = 32 ch = 64-B node row -> one edge-gather per slice is 4 lanes x 16 B
// = ONE fully-used cache line (was 16B-granular requests at the per-XCD L2
// request-rate ceiling). Slice (6.4 MB) is served by an XCD PAIR for C=128
// (quad for C=64): blockIdx%8 = slice*R + part, part picks the node subset.
// Block = 4 waves; each wave autonomously owns 16 nodes (lane: node=lane>>2,
// q=lane&3 -> 16 B chunk = 8 channels). Private LDS edge window per wave.
// Accumulation order per (node,channel) unchanged -> bitwise-identical output.
template <int C, int RELU, int POOL>
__global__ __launch_bounds__(256) void k_agg4(const unsigned short* __restrict__ P,
                                              const int* __restrict__ row_ptr,
                                              const int* __restrict__ srcs,
                                              const float* __restrict__ dinv,
                                              const float* __restrict__ bias,
                                              float* __restrict__ Hout,
                                              unsigned* __restrict__ minenc, int N) {
  const int NS2 = C / 32;      // 32-ch slices: 4 (C=128) or 2 (C=64)
  const int R = 8 / NS2;       // XCDs per slice: 2 or 4
  const int CAP = 448;         // 16-node group: mean 256 edges, sigma 16
  __shared__ int s_idx[4][CAP];
  __shared__ float s_red[4][32];
  int tid = threadIdx.x;
  int wv = tid >> 6, lane = tid & 63;
  int b8 = blockIdx.x & 7;
  int slice = b8 / R, part = b8 % R;
  int g0 = ((blockIdx.x >> 3) * R + part) * 64 + wv * 16;  // wave's 16-node base
  const char* Pb = (const char*)P + (size_t)slice * N * 64;

  int i = lane >> 2, q = lane & 3;
  unsigned qoff = (unsigned)q * 16u;
  int d = g0 + i;
  int dc = d < N ? d : N - 1;
  bool valid = d < N;

  int e0 = row_ptr[g0 < N ? g0 : N];
  int e1 = row_ptr[(g0 + 16) < N ? (g0 + 16) : N];
  int lo_n = row_ptr[dc];
  int hi_n = row_ptr[valid ? d + 1 : dc];

  float a[8];
  {  // self-loop term (clamped row for invalid lanes; never stored)
    uint4 v = *(const uint4*)(Pb + ((unsigned)dc * 64u + qoff));
    a[0] = __uint_as_float(v.x << 16);
    a[1] = __uint_as_float(v.x & 0xffff0000u);
    a[2] = __uint_as_float(v.y << 16);
    a[3] = __uint_as_float(v.y & 0xffff0000u);
    a[4] = __uint_as_float(v.z << 16);
    a[5] = __uint_as_float(v.z & 0xffff0000u);
    a[6] = __uint_as_float(v.w << 16);
    a[7] = __uint_as_float(v.w & 0xffff0000u);
  }

  for (int w0 = e0; w0 < e1; w0 += CAP) {
    int wend = min(w0 + CAP, e1);
    int cnt = wend - w0;
    __builtin_amdgcn_wave_barrier();
    for (int t = lane; t < cnt; t += 64) s_idx[wv][t] = srcs[w0 + t];
    __builtin_amdgcn_wave_barrier();
    int j = max(lo_n, w0), hi = min(hi_n, wend);
    for (; j + 2 <= hi; j += 2) {
      unsigned i0 = (unsigned)s_idx[wv][j - w0];
      unsigned i1 = (unsigned)s_idx[wv][j - w0 + 1];
      uint4 v0 = *(const uint4*)(Pb + (i0 * 64u + qoff));
      uint4 v1 = *(const uint4*)(Pb + (i1 * 64u + qoff));
      acc8(a, v0);
      acc8(a, v1);
    }
    if (j < hi) {
      unsigned i0 = (unsigned)s_idx[wv][j - w0];
      uint4 v0 = *(const uint4*)(Pb + (i0 * 64u + qoff));
      acc8(a, v0);
    }
  }

  int c0 = slice * 32 + q * 8;
  float dv = dinv[dc];
  float4 bv0 = *(const float4*)&bias[c0];
  float4 bv1 = *(const float4*)&bias[c0 + 4];
  float h[8];
  h[0] = dv * a[0] + bv0.x; h[1] = dv * a[1] + bv0.y;
  h[2] = dv * a[2] + bv0.z; h[3] = dv * a[3] + bv0.w;
  h[4] = dv * a[4] + bv1.x; h[5] = dv * a[5] + bv1.y;
  h[6] = dv * a[6] + bv1.z; h[7] = dv * a[7] + bv1.w;
  if (RELU) {
#pragma unroll
    for (int k = 0; k < 8; ++k) h[k] = fmaxf(h[k], 0.f);
  }

  if (POOL) {
    if (!valid) {
#pragma unroll
      for (int k = 0; k < 8; ++k) h[k] = FLT_MAX;
    }
    // min over the wave's 16 nodes: xor strides 4..32 preserve q = lane&3
#pragma unroll
    for (int off = 4; off < 64; off <<= 1) {
#pragma unroll
      for (int k = 0; k < 8; ++k) h[k] = fminf(h[k], __shfl_xor(h[k], off, 64));
    }
    if (lane < 4) {
#pragma unroll
      for (int k = 0; k < 8; ++k) s_red[wv][q * 8 + k] = h[k];
    }
    __syncthreads();
    if (tid < 32) {
      float m = fminf(fminf(s_red[0][tid], s_red[1][tid]),
                      fminf(s_red[2][tid], s_red[3][tid]));
      atomicMin(&minenc[slice * 32 + tid], enc_min(m));
    }
  } else if (valid) {
    float4 o0 = make_float4(h[0], h[1], h[2], h[3]);
    float4 o1 = make_float4(h[4], h[5], h[6], h[7]);
    *(float4*)&Hout[(size_t)d * C + c0] = o0;
    *(float4*)&Hout[(size_t)d * C + c0 + 4] = o1;
  }
}

__global__ void k_decode(const unsigned* __restrict__ minenc, float* __restrict__ out) {
  int c = threadIdx.x;
  unsigned k = minenc[c];
  unsigned u = (k & 0x80000000u) ? (k & 0x7FFFFFFFu) : ~k;
  out[c] = __uint_as_float(u);
}

// ---------------- launch ----------------
extern "C" void kernel_launch(void* const* d_in, const int* in_sizes, int n_in,
                              void* d_out, int out_size, void* d_ws, size_t ws_size,
                              hipStream_t stream) {
  const float* X  = (const float*)d_in[0];
  const int* edge = (const int*)d_in[1];
  const float* W1 = (const float*)d_in[2];
  const float* b1 = (const float*)d_in[3];
  const float* W2 = (const float*)d_in[4];
  const float* b2 = (const float*)d_in[5];
  const float* W3 = (const float*)d_in[6];
  const float* b3 = (const float*)d_in[7];
  float* out = (float*)d_out;

  const int IN_CH = 128;
  int N = in_sizes[0] / IN_CH;
  int E = in_sizes[1] / 2;

  char* ws = (char*)d_ws;
  size_t off = 0;
  auto alloc = [&](size_t bytes) {
    void* p = ws + off;
    off = (off + bytes + 255) & ~(size_t)255;
    return p;
  };
  unsigned short* P = (unsigned short*)alloc((size_t)N * 128 * 2);  // 25.6 MB bf16, sliced
  float* H       = (float*)alloc((size_t)N * 128 * 4);              // 51.2 MB
  int* srcs      = (int*)alloc((size_t)E * 4);                      // 6.4 MB
  int* cnt       = (int*)alloc((size_t)N * 4);
  int* incl      = (int*)alloc((size_t)N * 4);
  int* row_ptr   = (int*)alloc((size_t)(N + 1) * 4);
  int* cursor    = (int*)alloc((size_t)N * 4);
  float* dinv    = (float*)alloc((size_t)N * 4);
  int* bsum      = (int*)alloc(1024);
  int* boff      = (int*)alloc(1024);
  unsigned* minenc = (unsigned*)alloc(256);
  unsigned short* w1h = (unsigned short*)alloc(16384 * 2);
  unsigned short* w1l = (unsigned short*)alloc(16384 * 2);
  unsigned short* w2h = (unsigned short*)alloc(16384 * 2);
  unsigned short* w2l = (unsigned short*)alloc(16384 * 2);
  unsigned short* w3h = (unsigned short*)alloc(8192 * 2);
  unsigned short* w3l = (unsigned short*)alloc(8192 * 2);

  hipMemsetAsync(cnt, 0, (size_t)N * 4, stream);
  hipMemsetAsync(minenc, 0xFF, 64 * 4, stream);  // encoded +max

  int nb = (N + 1023) / 1024;
  k_prepw<<<160, 256, 0, stream>>>(W1, W2, W3, w1h, w1l, w2h, w2l, w3h, w3l);
  k_count<<<1024, 256, 0, stream>>>(edge, E, N, cnt);
  k_scan1<<<nb, 1024, 0, stream>>>(cnt, N, incl, bsum);
  k_scan2<<<1, 128, 0, stream>>>(bsum, nb, boff);
  k_aux<<<(N + 256) / 256, 256, 0, stream>>>(cnt, incl, boff, N, E, row_ptr, cursor, dinv);
  k_fill<<<1024, 256, 0, stream>>>(edge, E, N, cursor, srcs);

  int gx = (N + 63) / 64;
  int c128 = (N + 127) / 128;  // chunks for C=128 (R=2 parts x 64 nodes)
  int c64  = (N + 255) / 256;  // chunks for C=64  (R=4 parts x 64 nodes)
  // layer 1
  k_gemm_mfma<2><<<gx, 256, 0, stream>>>(X, w1h, w1l, dinv, P, N);
  k_agg4<128, 1, 0><<<c128 * 8, 256, 0, stream>>>(P, row_ptr, srcs, dinv, b1, H, minenc, N);
  // layer 2
  k_gemm_mfma<2><<<gx, 256, 0, stream>>>(H, w2h, w2l, dinv, P, N);
  k_agg4<128, 1, 0><<<c128 * 8, 256, 0, stream>>>(P, row_ptr, srcs, dinv, b2, H, minenc, N);
  // layer 3 (64 ch, no relu) with fused min-pool
  k_gemm_mfma<1><<<gx, 256, 0, stream>>>(H, w3h, w3l, dinv, P, N);
  k_agg4<64, 0, 1><<<c64 * 8, 256, 0, stream>>>(P, row_ptr, srcs, dinv, b3, nullptr, minenc, N);
  // decode encoded mins -> out[64]
  k_decode<<<1, 64, 0, stream>>>(minenc, out);
}